// Round 2
// baseline (119.676 us; speedup 1.0000x reference)
//
#include <hip/hip_runtime.h>
#include <hip/hip_bf16.h>

// QuanvolutionGraphQLClassifier — B=4096, 196 2x2-patches, 4-qubit circuit per
// patch, cosine-sim adjacency from sample 0, graph agg, linear 784->10,
// log_softmax. All tensors are FLOAT32 (reference dtype; R1's bf16 read of f32
// data produced the NaNs). Algebra: fold adj into W once ->
// W2[k,m*4+d] = sum_n adj[n,m] * W[k,n*4+d]; then logits[b,k] = meas_b . W2[k].

#define NP 196

// ---- 4-qubit statevector sim, 16 complex amps in registers ----------------
// amp index = w0*8 + w1*4 + w2*2 + w3 (matches reference (P,2,2,2,2) flatten).

template <int ST>
__device__ __forceinline__ void g_ry(float* re, float* im, float c, float s) {
#pragma unroll
  for (int i = 0; i < 16; ++i) {
    if (i & ST) continue;
    const int j = i | ST;
    float ar = re[i], ai = im[i], br = re[j], bi = im[j];
    re[i] = c * ar - s * br;  im[i] = c * ai - s * bi;
    re[j] = s * ar + c * br;  im[j] = s * ai + c * bi;
  }
}

template <int ST>
__device__ __forceinline__ void g_rx(float* re, float* im, float c, float s) {
  // [[c, -i s], [-i s, c]]
#pragma unroll
  for (int i = 0; i < 16; ++i) {
    if (i & ST) continue;
    const int j = i | ST;
    float ar = re[i], ai = im[i], br = re[j], bi = im[j];
    re[i] = c * ar + s * bi;  im[i] = c * ai - s * br;
    re[j] = c * br + s * ai;  im[j] = c * bi - s * ar;
  }
}

template <int ST>
__device__ __forceinline__ void g_rz(float* re, float* im, float c, float s) {
  // bit=0: *(c - i s); bit=1: *(c + i s)
#pragma unroll
  for (int i = 0; i < 16; ++i) {
    float r = re[i], q = im[i];
    if (i & ST) { re[i] = c * r - s * q; im[i] = c * q + s * r; }
    else        { re[i] = c * r + s * q; im[i] = c * q - s * r; }
  }
}

template <int STC, int STT>
__device__ __forceinline__ void g_cnot(float* re, float* im) {
#pragma unroll
  for (int i = 0; i < 16; ++i) {
    if ((i & STC) && !(i & STT)) {
      const int j = i | STT;
      float t = re[i]; re[i] = re[j]; re[j] = t;
      t = im[i]; im[i] = im[j]; im[j] = t;
    }
  }
}

// qc[i]=cos(p_i/2), qs[i]=sin(p_i/2). FAST=1 -> __sincosf for the encoder.
template <int FAST>
__device__ __forceinline__ void qsim(float a0, float a1, float a2, float a3,
                                     const float* qc, const float* qs,
                                     float* e) {
  float c0, s0, c1, s1, c2, s2, c3, s3;
  if (FAST) {
    __sincosf(0.5f * a0, &s0, &c0);
    __sincosf(0.5f * a1, &s1, &c1);
    __sincosf(0.5f * a2, &s2, &c2);
    __sincosf(0.5f * a3, &s3, &c3);
  } else {
    sincosf(0.5f * a0, &s0, &c0);
    sincosf(0.5f * a1, &s1, &c1);
    sincosf(0.5f * a2, &s2, &c2);
    sincosf(0.5f * a3, &s3, &c3);
  }
  float r0[2] = {c0, s0}, r1[2] = {c1, s1}, r2[2] = {c2, s2}, r3[2] = {c3, s3};
  float re[16], im[16];
#pragma unroll
  for (int i = 0; i < 16; ++i) {
    re[i] = r0[(i >> 3) & 1] * r1[(i >> 2) & 1] * r2[(i >> 1) & 1] * r3[i & 1];
    im[i] = 0.0f;
  }
  // RX(p0)w0; RY(p1)w1; RZ(p2)w2; CNOT(0,1); RX(p3)w3; CNOT(2,3);
  // RY(p4)w0; RZ(p5)w3
  g_rx<8>(re, im, qc[0], qs[0]);
  g_ry<4>(re, im, qc[1], qs[1]);
  g_rz<2>(re, im, qc[2], qs[2]);
  g_cnot<8, 4>(re, im);
  g_rx<1>(re, im, qc[3], qs[3]);
  g_cnot<2, 1>(re, im);
  g_ry<8>(re, im, qc[4], qs[4]);
  g_rz<1>(re, im, qc[5], qs[5]);
  float ez[4] = {0.f, 0.f, 0.f, 0.f};
#pragma unroll
  for (int i = 0; i < 16; ++i) {
    float p = re[i] * re[i] + im[i] * im[i];
    ez[0] += (i & 8) ? -p : p;
    ez[1] += (i & 4) ? -p : p;
    ez[2] += (i & 2) ? -p : p;
    ez[3] += (i & 1) ? -p : p;
  }
  e[0] = ez[0]; e[1] = ez[1]; e[2] = ez[2]; e[3] = ez[3];
}

__device__ __forceinline__ void load_qtrig(const float* qp, float* qc, float* qs) {
#pragma unroll
  for (int i = 0; i < 6; ++i) sincosf(0.5f * qp[i], &qs[i], &qc[i]);
}

// ---- K1: sample-0 measurements + adjacency (one block) --------------------
__global__ __launch_bounds__(256) void k_adj(const float* __restrict__ x,
                                             const float* __restrict__ qp,
                                             float* __restrict__ adj) {
  __shared__ float v[NP][4];
  __shared__ float nrm[NP];
  int t = threadIdx.x;
  if (t < NP) {
    float qc[6], qs[6];
    load_qtrig(qp, qc, qs);
    int i = t / 14, j = t % 14;
    float a0 = x[(2 * i) * 28 + 2 * j];
    float a1 = x[(2 * i) * 28 + 2 * j + 1];
    float a2 = x[(2 * i + 1) * 28 + 2 * j];
    float a3 = x[(2 * i + 1) * 28 + 2 * j + 1];
    float e[4];
    qsim<0>(a0, a1, a2, a3, qc, qs, e);
    v[t][0] = e[0]; v[t][1] = e[1]; v[t][2] = e[2]; v[t][3] = e[3];
    nrm[t] = sqrtf(e[0] * e[0] + e[1] * e[1] + e[2] * e[2] + e[3] * e[3]);
  }
  __syncthreads();
  for (int idx = t; idx < NP * NP; idx += 256) {
    int n = idx / NP, m = idx % NP;
    float dot = v[n][0] * v[m][0] + v[n][1] * v[m][1] +
                v[n][2] * v[m][2] + v[n][3] * v[m][3];
    float sim = dot / (nrm[n] * nrm[m] + 1e-12f);
    adj[idx] = (sim >= 0.9f) ? 1.0f : ((sim >= 0.5f) ? 0.5f : 0.0f);
  }
}

// ---- K2: W2[k, m*4+d] = sum_n adj[n,m] * W[k, n*4+d] ----------------------
__global__ __launch_bounds__(256) void k_w2(const float* __restrict__ adj,
                                            const float* __restrict__ W,
                                            float* __restrict__ W2) {
  int t = blockIdx.x * 256 + threadIdx.x;
  if (t >= 10 * 784) return;
  int k = t / 784, c = t % 784;
  int m = c >> 2, d = c & 3;
  float acc = 0.0f;
  for (int n = 0; n < NP; ++n)
    acc += adj[n * NP + m] * W[k * 784 + n * 4 + d];
  W2[t] = acc;
}

// ---- K3: per sample: measure patches, dot vs W2, log_softmax --------------
__global__ __launch_bounds__(256) void k_main(const float* __restrict__ x,
                                              const float* __restrict__ qp,
                                              const float* __restrict__ bias,
                                              const float* __restrict__ W2,
                                              float* __restrict__ out) {
  int b = blockIdx.x, t = threadIdx.x;
  __shared__ float ximg[784];
  __shared__ float meas[784];
  __shared__ float partial[4 * 10];
  __shared__ float logits[10];
  __shared__ float lse;

  const float* xb = x + (size_t)b * 784;
  if (t < NP) {  // 196 * float4 = 784 floats; b*3136 is 16B aligned
    float4 u = ((const float4*)xb)[t];
    ximg[4 * t + 0] = u.x;
    ximg[4 * t + 1] = u.y;
    ximg[4 * t + 2] = u.z;
    ximg[4 * t + 3] = u.w;
  }
  __syncthreads();
  if (t < NP) {
    float qc[6], qs[6];
    load_qtrig(qp, qc, qs);
    int i = t / 14, j = t % 14;
    float a0 = ximg[(2 * i) * 28 + 2 * j];
    float a1 = ximg[(2 * i) * 28 + 2 * j + 1];
    float a2 = ximg[(2 * i + 1) * 28 + 2 * j];
    float a3 = ximg[(2 * i + 1) * 28 + 2 * j + 1];
    float e[4];
    qsim<1>(a0, a1, a2, a3, qc, qs, e);
    meas[4 * t + 0] = e[0]; meas[4 * t + 1] = e[1];
    meas[4 * t + 2] = e[2]; meas[4 * t + 3] = e[3];
  }
  __syncthreads();
  float acc[10];
#pragma unroll
  for (int k = 0; k < 10; ++k) acc[k] = 0.0f;
  for (int e = t; e < 784; e += 256) {
    float mv = meas[e];
#pragma unroll
    for (int k = 0; k < 10; ++k) acc[k] += mv * W2[k * 784 + e];
  }
#pragma unroll
  for (int k = 0; k < 10; ++k)
#pragma unroll
    for (int off = 32; off; off >>= 1) acc[k] += __shfl_down(acc[k], off);
  int wid = t >> 6, lane = t & 63;
  if (lane == 0) {
#pragma unroll
    for (int k = 0; k < 10; ++k) partial[wid * 10 + k] = acc[k];
  }
  __syncthreads();
  if (t < 10) {
    logits[t] = bias[t] + partial[t] + partial[10 + t] +
                partial[20 + t] + partial[30 + t];
  }
  __syncthreads();
  if (t == 0) {
    float m = logits[0];
#pragma unroll
    for (int k = 1; k < 10; ++k) m = fmaxf(m, logits[k]);
    float s = 0.0f;
#pragma unroll
    for (int k = 0; k < 10; ++k) s += __expf(logits[k] - m);
    lse = m + __logf(s);
  }
  __syncthreads();
  if (t < 10) out[(size_t)b * 10 + t] = logits[t] - lse;
}

extern "C" void kernel_launch(void* const* d_in, const int* in_sizes, int n_in,
                              void* d_out, int out_size, void* d_ws, size_t ws_size,
                              hipStream_t stream) {
  const float* x  = (const float*)d_in[0];  // (B,1,28,28) f32
  const float* qp = (const float*)d_in[1];  // (6,) f32
  const float* W  = (const float*)d_in[2];  // (10,784) f32
  const float* bi = (const float*)d_in[3];  // (10,) f32
  float* out = (float*)d_out;               // (B,10) f32

  int Bsz = in_sizes[0] / 784;

  float* adj = (float*)d_ws;            // 196*196 f32
  float* W2  = adj + NP * NP;           // 10*784 f32  (~185 KB total)

  k_adj<<<1, 256, 0, stream>>>(x, qp, adj);
  k_w2<<<(10 * 784 + 255) / 256, 256, 0, stream>>>(adj, W, W2);
  k_main<<<Bsz, 256, 0, stream>>>(x, qp, bi, W2, out);
}

// Round 3
// 104.009 us; speedup vs baseline: 1.1506x; 1.1506x over previous
//
#include <hip/hip_runtime.h>
#include <hip/hip_bf16.h>

// QuanvolutionGraphQLClassifier — f32 in/out. Pipeline:
//  K1 (1 blk): sample-0 patch measurements v[196][4], norms, q-trig -> ws
//  K2 (196 blk): adjacency row m recomputed on the fly (sim symmetric),
//                folded into W2[k, 4m+d] = sum_n w(m,n) * W[k, 4n+d]
//  K3 (B blk):  per-sample: regs-only patch qsim, dot vs W2, log_softmax

#define NP 196

// ---- 4-qubit statevector sim, 16 complex amps in registers ----------------
// amp index = w0*8 + w1*4 + w2*2 + w3 (matches reference (P,2,2,2,2) flatten).

template <int ST>
__device__ __forceinline__ void g_ry(float* re, float* im, float c, float s) {
#pragma unroll
  for (int i = 0; i < 16; ++i) {
    if (i & ST) continue;
    const int j = i | ST;
    float ar = re[i], ai = im[i], br = re[j], bi = im[j];
    re[i] = c * ar - s * br;  im[i] = c * ai - s * bi;
    re[j] = s * ar + c * br;  im[j] = s * ai + c * bi;
  }
}

template <int ST>
__device__ __forceinline__ void g_rx(float* re, float* im, float c, float s) {
  // [[c, -i s], [-i s, c]]
#pragma unroll
  for (int i = 0; i < 16; ++i) {
    if (i & ST) continue;
    const int j = i | ST;
    float ar = re[i], ai = im[i], br = re[j], bi = im[j];
    re[i] = c * ar + s * bi;  im[i] = c * ai - s * br;
    re[j] = c * br + s * ai;  im[j] = c * bi - s * ar;
  }
}

template <int ST>
__device__ __forceinline__ void g_rz(float* re, float* im, float c, float s) {
  // bit=0: *(c - i s); bit=1: *(c + i s)
#pragma unroll
  for (int i = 0; i < 16; ++i) {
    float r = re[i], q = im[i];
    if (i & ST) { re[i] = c * r - s * q; im[i] = c * q + s * r; }
    else        { re[i] = c * r + s * q; im[i] = c * q - s * r; }
  }
}

template <int STC, int STT>
__device__ __forceinline__ void g_cnot(float* re, float* im) {
#pragma unroll
  for (int i = 0; i < 16; ++i) {
    if ((i & STC) && !(i & STT)) {
      const int j = i | STT;
      float t = re[i]; re[i] = re[j]; re[j] = t;
      t = im[i]; im[i] = im[j]; im[j] = t;
    }
  }
}

// qc[i]=cos(p_i/2), qs[i]=sin(p_i/2). FAST: __sincosf for the encoder angles.
template <int FAST>
__device__ __forceinline__ void qsim(float a0, float a1, float a2, float a3,
                                     const float* qc, const float* qs,
                                     float* e) {
  float c0, s0, c1, s1, c2, s2, c3, s3;
  if (FAST) {
    __sincosf(0.5f * a0, &s0, &c0);
    __sincosf(0.5f * a1, &s1, &c1);
    __sincosf(0.5f * a2, &s2, &c2);
    __sincosf(0.5f * a3, &s3, &c3);
  } else {
    sincosf(0.5f * a0, &s0, &c0);
    sincosf(0.5f * a1, &s1, &c1);
    sincosf(0.5f * a2, &s2, &c2);
    sincosf(0.5f * a3, &s3, &c3);
  }
  float r0[2] = {c0, s0}, r1[2] = {c1, s1}, r2[2] = {c2, s2}, r3[2] = {c3, s3};
  float re[16], im[16];
#pragma unroll
  for (int i = 0; i < 16; ++i) {
    re[i] = r0[(i >> 3) & 1] * r1[(i >> 2) & 1] * r2[(i >> 1) & 1] * r3[i & 1];
    im[i] = 0.0f;
  }
  // RX(p0)w0; RY(p1)w1; RZ(p2)w2; CNOT(0,1); RX(p3)w3; CNOT(2,3);
  // RY(p4)w0; RZ(p5)w3
  g_rx<8>(re, im, qc[0], qs[0]);
  g_ry<4>(re, im, qc[1], qs[1]);
  g_rz<2>(re, im, qc[2], qs[2]);
  g_cnot<8, 4>(re, im);
  g_rx<1>(re, im, qc[3], qs[3]);
  g_cnot<2, 1>(re, im);
  g_ry<8>(re, im, qc[4], qs[4]);
  g_rz<1>(re, im, qc[5], qs[5]);
  float ez[4] = {0.f, 0.f, 0.f, 0.f};
#pragma unroll
  for (int i = 0; i < 16; ++i) {
    float p = re[i] * re[i] + im[i] * im[i];
    ez[0] += (i & 8) ? -p : p;
    ez[1] += (i & 4) ? -p : p;
    ez[2] += (i & 2) ? -p : p;
    ez[3] += (i & 1) ? -p : p;
  }
  e[0] = ez[0]; e[1] = ez[1]; e[2] = ez[2]; e[3] = ez[3];
}

// ---- K1: sample-0 measurements + norms + q-trig -> ws ---------------------
__global__ __launch_bounds__(256) void k_meas0(const float* __restrict__ x,
                                               const float* __restrict__ qp,
                                               float* __restrict__ vG,     // [196*4]
                                               float* __restrict__ nrmG,   // [196]
                                               float* __restrict__ qtG) {  // [12]
  int t = threadIdx.x;
  if (t < 6) {
    float c, s;
    sincosf(0.5f * qp[t], &s, &c);
    qtG[t] = c;
    qtG[6 + t] = s;
  }
  if (t < NP) {
    float qc[6], qs[6];
#pragma unroll
    for (int i = 0; i < 6; ++i) sincosf(0.5f * qp[i], &qs[i], &qc[i]);
    int i = t / 14, j = t % 14;
    float a0 = x[(2 * i) * 28 + 2 * j];
    float a1 = x[(2 * i) * 28 + 2 * j + 1];
    float a2 = x[(2 * i + 1) * 28 + 2 * j];
    float a3 = x[(2 * i + 1) * 28 + 2 * j + 1];
    float e[4];
    qsim<0>(a0, a1, a2, a3, qc, qs, e);
    vG[4 * t + 0] = e[0]; vG[4 * t + 1] = e[1];
    vG[4 * t + 2] = e[2]; vG[4 * t + 3] = e[3];
    nrmG[t] = sqrtf(e[0] * e[0] + e[1] * e[1] + e[2] * e[2] + e[3] * e[3]);
  }
}

// ---- K2: block m: adjacency row m on the fly, fold into W2[k, 4m+d] -------
__global__ __launch_bounds__(64) void k_w2(const float* __restrict__ vG,
                                           const float* __restrict__ nrmG,
                                           const float* __restrict__ W,
                                           float* __restrict__ W2) {
  __shared__ float wrow[NP];
  int m = blockIdx.x, lane = threadIdx.x;
  float v0 = vG[4 * m], v1 = vG[4 * m + 1], v2 = vG[4 * m + 2], v3 = vG[4 * m + 3];
  float nm = nrmG[m];
  for (int c = lane; c < NP; c += 64) {
    float4 vc = ((const float4*)vG)[c];
    float dot = v0 * vc.x + v1 * vc.y + v2 * vc.z + v3 * vc.w;
    float sim = dot / (nm * nrmG[c] + 1e-12f);  // sim symmetric => adj[c,m]
    wrow[c] = (sim >= 0.9f) ? 1.0f : ((sim >= 0.5f) ? 0.5f : 0.0f);
  }
  __syncthreads();
  if (lane < 40) {
    int k = lane >> 2, d = lane & 3;
    const float* Wk = W + k * 784 + d;
    float acc = 0.0f;
#pragma unroll 4
    for (int n = 0; n < NP; ++n) acc += wrow[n] * Wk[4 * n];
    W2[k * 784 + 4 * m + d] = acc;
  }
}

// ---- K3: per sample: regs-only qsim, dot vs W2, log_softmax ---------------
__global__ __launch_bounds__(256) void k_main(const float* __restrict__ x,
                                              const float* __restrict__ qtG,
                                              const float* __restrict__ bias,
                                              const float* __restrict__ W2,
                                              float* __restrict__ out) {
  int b = blockIdx.x, t = threadIdx.x;
  __shared__ float partial[4 * 10];
  __shared__ float logits[10];
  __shared__ float lse;

  float acc[10];
#pragma unroll
  for (int k = 0; k < 10; ++k) acc[k] = 0.0f;

  if (t < NP) {
    float qc[6], qs[6];
#pragma unroll
    for (int i = 0; i < 6; ++i) { qc[i] = qtG[i]; qs[i] = qtG[6 + i]; }
    int i = t / 14, j = t % 14;
    const float* xb = x + (size_t)b * 784;
    float2 top = *(const float2*)(xb + (2 * i) * 28 + 2 * j);
    float2 bot = *(const float2*)(xb + (2 * i + 1) * 28 + 2 * j);
    float e[4];
    qsim<1>(top.x, top.y, bot.x, bot.y, qc, qs, e);
    // thread t owns meas elements 4t..4t+3; fold into all 10 logits
#pragma unroll
    for (int k = 0; k < 10; ++k) {
      float4 w = *(const float4*)(W2 + k * 784 + 4 * t);
      acc[k] = e[0] * w.x + e[1] * w.y + e[2] * w.z + e[3] * w.w;
    }
  }
  // wave-64 reduce (lanes >=196 contribute zeros)
#pragma unroll
  for (int k = 0; k < 10; ++k)
#pragma unroll
    for (int off = 32; off; off >>= 1) acc[k] += __shfl_down(acc[k], off);
  int wid = t >> 6, lane = t & 63;
  if (lane == 0) {
#pragma unroll
    for (int k = 0; k < 10; ++k) partial[wid * 10 + k] = acc[k];
  }
  __syncthreads();
  if (t < 10) {
    logits[t] = bias[t] + partial[t] + partial[10 + t] +
                partial[20 + t] + partial[30 + t];
  }
  __syncthreads();
  if (t == 0) {
    float m = logits[0];
#pragma unroll
    for (int k = 1; k < 10; ++k) m = fmaxf(m, logits[k]);
    float s = 0.0f;
#pragma unroll
    for (int k = 0; k < 10; ++k) s += __expf(logits[k] - m);
    lse = m + __logf(s);
  }
  __syncthreads();
  if (t < 10) out[(size_t)b * 10 + t] = logits[t] - lse;
}

extern "C" void kernel_launch(void* const* d_in, const int* in_sizes, int n_in,
                              void* d_out, int out_size, void* d_ws, size_t ws_size,
                              hipStream_t stream) {
  const float* x  = (const float*)d_in[0];  // (B,1,28,28) f32
  const float* qp = (const float*)d_in[1];  // (6,) f32
  const float* W  = (const float*)d_in[2];  // (10,784) f32
  const float* bi = (const float*)d_in[3];  // (10,) f32
  float* out = (float*)d_out;               // (B,10) f32

  int Bsz = in_sizes[0] / 784;

  float* vG   = (float*)d_ws;        // 784 f32 (16B-aligned base)
  float* nrmG = vG + 784;            // 196
  float* qtG  = nrmG + 196;          // 12
  float* W2   = qtG + 12;            // 7840

  k_meas0<<<1, 256, 0, stream>>>(x, qp, vG, nrmG, qtG);
  k_w2<<<NP, 64, 0, stream>>>(vG, nrmG, W, W2);
  k_main<<<Bsz, 256, 0, stream>>>(x, qtG, bi, W2, out);
}

// Round 4
// 93.738 us; speedup vs baseline: 1.2767x; 1.1096x over previous
//
#include <hip/hip_runtime.h>
#include <hip/hip_bf16.h>

// QuanvolutionGraphQLClassifier — f32 in/out.
// Circuit factorizes: wires {0,1} and {2,3} never entangle with each other.
// Each Pauli-Z expectation is a bilinear form  e_d = wA . H_d . wB  where
// w(q) = (cos^2(a/2), cos(a/2)sin(a/2), sin^2(a/2)) per qubit and H_d is a
// fixed 3x3 matrix derived from q_params once (K1).
//  K1 (1 blk): build subsystem unitaries -> H[4][9]; sample-0 v, norms.
//  K2 (196 blk): adjacency row m on the fly, fold into W2[k,4m+d].
//  K3 (B/4 blk): one wave per sample; per lane ~3 patches; butterfly reduce.

#define NP 196

__device__ __forceinline__ float quad3(const float* H, const float* wa,
                                       const float* wb) {
  return wa[0] * (H[0] * wb[0] + H[1] * wb[1] + H[2] * wb[2]) +
         wa[1] * (H[3] * wb[0] + H[4] * wb[1] + H[5] * wb[2]) +
         wa[2] * (H[6] * wb[0] + H[7] * wb[1] + H[8] * wb[2]);
}

// ---- K1: H tables + sample-0 measurements ---------------------------------
__global__ __launch_bounds__(256) void k_prep(const float* __restrict__ x,
                                              const float* __restrict__ qp,
                                              float* __restrict__ vG,    // 784
                                              float* __restrict__ nrmG,  // 196
                                              float* __restrict__ HG) {  // 36
  __shared__ float Hs[36];
  int t = threadIdx.x;
  if (t < 2) {
    float qc[6], qs[6];
#pragma unroll
    for (int i = 0; i < 6; ++i) sincosf(0.5f * qp[i], &qs[i], &qc[i]);
    float Mr[4][4] = {}, Mi[4][4] = {};
    if (t == 0) {
      // Subsystem A (wires 0,1), index = 2*b0 + b1.
      // U_A = RY(q4,w0) * CNOT01 * RY(q1,w1) * RX(q0,w0)
      Mr[0][0] = Mr[1][1] = Mr[2][2] = Mr[3][3] = qc[0];   // RX(q0) on w0
      Mi[0][2] = Mi[2][0] = Mi[1][3] = Mi[3][1] = -qs[0];
      for (int j = 0; j < 4; ++j) {  // RY(q1) on w1: rows (0,1),(2,3)
        float a, b;
        a = Mr[0][j]; b = Mr[1][j]; Mr[0][j] = qc[1]*a - qs[1]*b; Mr[1][j] = qs[1]*a + qc[1]*b;
        a = Mi[0][j]; b = Mi[1][j]; Mi[0][j] = qc[1]*a - qs[1]*b; Mi[1][j] = qs[1]*a + qc[1]*b;
        a = Mr[2][j]; b = Mr[3][j]; Mr[2][j] = qc[1]*a - qs[1]*b; Mr[3][j] = qs[1]*a + qc[1]*b;
        a = Mi[2][j]; b = Mi[3][j]; Mi[2][j] = qc[1]*a - qs[1]*b; Mi[3][j] = qs[1]*a + qc[1]*b;
      }
      for (int j = 0; j < 4; ++j) {  // CNOT(0,1): swap rows 2,3
        float r = Mr[2][j]; Mr[2][j] = Mr[3][j]; Mr[3][j] = r;
        float q = Mi[2][j]; Mi[2][j] = Mi[3][j]; Mi[3][j] = q;
      }
      for (int j = 0; j < 4; ++j) {  // RY(q4) on w0: rows (0,2),(1,3)
        float a, b;
        a = Mr[0][j]; b = Mr[2][j]; Mr[0][j] = qc[4]*a - qs[4]*b; Mr[2][j] = qs[4]*a + qc[4]*b;
        a = Mi[0][j]; b = Mi[2][j]; Mi[0][j] = qc[4]*a - qs[4]*b; Mi[2][j] = qs[4]*a + qc[4]*b;
        a = Mr[1][j]; b = Mr[3][j]; Mr[1][j] = qc[4]*a - qs[4]*b; Mr[3][j] = qs[4]*a + qc[4]*b;
        a = Mi[1][j]; b = Mi[3][j]; Mi[1][j] = qc[4]*a - qs[4]*b; Mi[3][j] = qs[4]*a + qc[4]*b;
      }
    } else {
      // Subsystem B (wires 2,3), index = 2*b2 + b3.
      // U_B = RZ(q5,w3) * CNOT23 * RX(q3,w3) * RZ(q2,w2)
      Mr[0][0] = Mr[1][1] = Mr[2][2] = Mr[3][3] = qc[2];   // RZ(q2) on w2
      Mi[0][0] = Mi[1][1] = -qs[2]; Mi[2][2] = Mi[3][3] = qs[2];
      for (int j = 0; j < 4; ++j) {  // RX(q3) on w3: rows (0,1),(2,3)
        float ra, ia, rb, ib;
        ra = Mr[0][j]; ia = Mi[0][j]; rb = Mr[1][j]; ib = Mi[1][j];
        Mr[0][j] = qc[3]*ra + qs[3]*ib;  Mi[0][j] = qc[3]*ia - qs[3]*rb;
        Mr[1][j] = qc[3]*rb + qs[3]*ia;  Mi[1][j] = qc[3]*ib - qs[3]*ra;
        ra = Mr[2][j]; ia = Mi[2][j]; rb = Mr[3][j]; ib = Mi[3][j];
        Mr[2][j] = qc[3]*ra + qs[3]*ib;  Mi[2][j] = qc[3]*ia - qs[3]*rb;
        Mr[3][j] = qc[3]*rb + qs[3]*ia;  Mi[3][j] = qc[3]*ib - qs[3]*ra;
      }
      for (int j = 0; j < 4; ++j) {  // CNOT(2,3): swap rows 2,3
        float r = Mr[2][j]; Mr[2][j] = Mr[3][j]; Mr[3][j] = r;
        float q = Mi[2][j]; Mi[2][j] = Mi[3][j]; Mi[3][j] = q;
      }
      for (int r = 0; r < 4; ++r) {  // RZ(q5) on w3: rows 0,2: *(c5-is5); 1,3: *(c5+is5)
        float sg = (r & 1) ? 1.0f : -1.0f;
        for (int j = 0; j < 4; ++j) {
          float re = Mr[r][j], im = Mi[r][j];
          Mr[r][j] = qc[5] * re - sg * qs[5] * im;
          Mi[r][j] = qc[5] * im + sg * qs[5] * re;
        }
      }
    }
    // G_d[j][k] = sum_i sigma_i (Re U_ij Re U_ik + Im U_ij Im U_ik);
    // d=0: sign by high bit (rows 0,1 + / 2,3 -); d=1: by low bit (0,2 + / 1,3 -)
    for (int d = 0; d < 2; ++d) {
      float G[4][4];
      for (int j = 0; j < 4; ++j)
        for (int k = 0; k < 4; ++k) {
          float g = 0.0f;
          for (int i = 0; i < 4; ++i) {
            float sg = (d == 0) ? ((i < 2) ? 1.f : -1.f)
                                : (((i & 1) == 0) ? 1.f : -1.f);
            g += sg * (Mr[i][j] * Mr[i][k] + Mi[i][j] * Mi[i][k]);
          }
          G[j][k] = g;
        }
      float* H = Hs + t * 18 + d * 9;  // A -> Hs[0..17], B -> Hs[18..35]
      H[0] = G[0][0];       H[1] = 2.f * G[0][1];               H[2] = G[1][1];
      H[3] = 2.f * G[0][2]; H[4] = 2.f * (G[0][3] + G[1][2]);   H[5] = 2.f * G[1][3];
      H[6] = G[2][2];       H[7] = 2.f * G[2][3];               H[8] = G[3][3];
    }
  }
  __syncthreads();
  if (t < 36) HG[t] = Hs[t];
  if (t < NP) {
    int i = t / 14, j = t % 14;
    float2 top = *(const float2*)(x + 56 * i + 2 * j);
    float2 bot = *(const float2*)(x + 56 * i + 28 + 2 * j);
    float c0, s0, c1, s1, c2, s2, c3, s3;
    sincosf(0.5f * top.x, &s0, &c0);
    sincosf(0.5f * top.y, &s1, &c1);
    sincosf(0.5f * bot.x, &s2, &c2);
    sincosf(0.5f * bot.y, &s3, &c3);
    float wA0[3] = {c0 * c0, c0 * s0, s0 * s0};
    float wA1[3] = {c1 * c1, c1 * s1, s1 * s1};
    float wB0[3] = {c2 * c2, c2 * s2, s2 * s2};
    float wB1[3] = {c3 * c3, c3 * s3, s3 * s3};
    float e0 = quad3(Hs, wA0, wA1), e1 = quad3(Hs + 9, wA0, wA1);
    float e2 = quad3(Hs + 18, wB0, wB1), e3 = quad3(Hs + 27, wB0, wB1);
    vG[4 * t] = e0; vG[4 * t + 1] = e1; vG[4 * t + 2] = e2; vG[4 * t + 3] = e3;
    nrmG[t] = sqrtf(e0 * e0 + e1 * e1 + e2 * e2 + e3 * e3);
  }
}

// ---- K2: block m: adjacency row m, fold into W2[k, 4m+d] ------------------
__global__ __launch_bounds__(64) void k_w2(const float* __restrict__ vG,
                                           const float* __restrict__ nrmG,
                                           const float* __restrict__ W,
                                           float* __restrict__ W2) {
  __shared__ float wrow[NP];
  int m = blockIdx.x, lane = threadIdx.x;
  float v0 = vG[4 * m], v1 = vG[4 * m + 1], v2 = vG[4 * m + 2], v3 = vG[4 * m + 3];
  float nm = nrmG[m];
  for (int c = lane; c < NP; c += 64) {
    float4 vc = ((const float4*)vG)[c];
    float dot = v0 * vc.x + v1 * vc.y + v2 * vc.z + v3 * vc.w;
    float sim = dot / (nm * nrmG[c] + 1e-12f);  // symmetric
    wrow[c] = (sim >= 0.9f) ? 1.0f : ((sim >= 0.5f) ? 0.5f : 0.0f);
  }
  __syncthreads();
  if (lane < 40) {
    int k = lane >> 2, d = lane & 3;
    const float* Wk = W + k * 784 + d;
    float acc = 0.0f;
#pragma unroll 4
    for (int n = 0; n < NP; ++n) acc += wrow[n] * Wk[4 * n];
    W2[k * 784 + 4 * m + d] = acc;
  }
}

// ---- K3: one wave per sample ----------------------------------------------
__global__ __launch_bounds__(256) void k_main(const float* __restrict__ x,
                                              const float* __restrict__ HG,
                                              const float* __restrict__ bias,
                                              const float* __restrict__ W2,
                                              float* __restrict__ out, int Bsz) {
  int t = threadIdx.x, wv = t >> 6, lane = t & 63;
  int b = blockIdx.x * 4 + wv;
  if (b >= Bsz) return;

  float H[36];
#pragma unroll
  for (int i = 0; i < 36; ++i) H[i] = HG[i];  // loop-invariant, regs
  float bv[10];
#pragma unroll
  for (int k = 0; k < 10; ++k) bv[k] = bias[k];

  const float* xb = x + (size_t)b * 784;
  float acc[10];
#pragma unroll
  for (int k = 0; k < 10; ++k) acc[k] = 0.0f;

#pragma unroll
  for (int r = 0; r < 4; ++r) {
    int p = lane + 64 * r;
    if (p < NP) {
      int i = p / 14, j = p - 14 * i;
      float2 top = *(const float2*)(xb + 56 * i + 2 * j);
      float2 bot = *(const float2*)(xb + 56 * i + 28 + 2 * j);
      float c0, s0, c1, s1, c2, s2, c3, s3;
      __sincosf(0.5f * top.x, &s0, &c0);
      __sincosf(0.5f * top.y, &s1, &c1);
      __sincosf(0.5f * bot.x, &s2, &c2);
      __sincosf(0.5f * bot.y, &s3, &c3);
      float wA0[3] = {c0 * c0, c0 * s0, s0 * s0};
      float wA1[3] = {c1 * c1, c1 * s1, s1 * s1};
      float wB0[3] = {c2 * c2, c2 * s2, s2 * s2};
      float wB1[3] = {c3 * c3, c3 * s3, s3 * s3};
      float e0 = quad3(H, wA0, wA1), e1 = quad3(H + 9, wA0, wA1);
      float e2 = quad3(H + 18, wB0, wB1), e3 = quad3(H + 27, wB0, wB1);
#pragma unroll
      for (int k = 0; k < 10; ++k) {
        float4 w = *(const float4*)(W2 + k * 784 + 4 * p);
        acc[k] += e0 * w.x + e1 * w.y + e2 * w.z + e3 * w.w;
      }
    }
  }
  // butterfly: every lane ends with all 10 totals
#pragma unroll
  for (int k = 0; k < 10; ++k)
#pragma unroll
    for (int off = 32; off; off >>= 1) acc[k] += __shfl_xor(acc[k], off);

  float lg[10], m = -1e30f;
#pragma unroll
  for (int k = 0; k < 10; ++k) { lg[k] = acc[k] + bv[k]; m = fmaxf(m, lg[k]); }
  float s = 0.0f;
#pragma unroll
  for (int k = 0; k < 10; ++k) s += __expf(lg[k] - m);
  float lse = m + __logf(s);
  if (lane < 10) {
    float sel = lg[0];
#pragma unroll
    for (int k = 1; k < 10; ++k) sel = (lane == k) ? lg[k] : sel;
    out[(size_t)b * 10 + lane] = sel - lse;
  }
}

extern "C" void kernel_launch(void* const* d_in, const int* in_sizes, int n_in,
                              void* d_out, int out_size, void* d_ws, size_t ws_size,
                              hipStream_t stream) {
  const float* x  = (const float*)d_in[0];  // (B,1,28,28) f32
  const float* qp = (const float*)d_in[1];  // (6,) f32
  const float* W  = (const float*)d_in[2];  // (10,784) f32
  const float* bi = (const float*)d_in[3];  // (10,) f32
  float* out = (float*)d_out;               // (B,10) f32

  int Bsz = in_sizes[0] / 784;

  float* vG   = (float*)d_ws;        // 784
  float* nrmG = vG + 784;            // 196
  float* HG   = nrmG + 196;          // 36
  float* W2   = HG + 36;             // 7840

  k_prep<<<1, 256, 0, stream>>>(x, qp, vG, nrmG, HG);
  k_w2<<<NP, 64, 0, stream>>>(vG, nrmG, W, W2);
  k_main<<<(Bsz + 3) / 4, 256, 0, stream>>>(x, HG, bi, W2, out, Bsz);
}